// Round 16
// baseline (52.828 us; speedup 1.0000x reference)
//
#include <hip/hip_runtime.h>
#include <hip/hip_fp16.h>

#define Hh 512
#define Ww 512
#define Bb 2
#define Gg 4
#define Ff 9
#define Cc 3
#define Nn (Hh*Ww)

#define TILE 32
#define RS 36          // fM region: tile + halo 2
#define RSP 37         // padded row stride (bank-rotate)
#define DS 34          // dinv region: tile + halo 1
#define DSP 35         // padded row stride
#define NT 256         // each thread owns a 2x2 pixel quad

struct __align__(16) FmVec { __half2 h[4]; };   // f0..f7 -> one ds_read_b128

struct FmPt { __half2 a0, a1, b0, b1; float cf; };

__device__ __forceinline__ float dotfm(const FmPt& p, const FmPt& q) {
    __half2 acc = __hmul2(p.a0, q.a0);
    acc = __hfma2(p.a1, q.a1, acc);
    acc = __hfma2(p.b0, q.b0, acc);
    acc = __hfma2(p.b1, q.b1, acc);
    return __low2float(acc) + __high2float(acc) + p.cf * q.cf;
}

// |sim| <= |fM_p||fM_q| ~= 0.27 << 10 -> reference clamp never fires; skip it.
__device__ __forceinline__ float ew_of(float s) { return __expf(s); }

__global__ void __launch_bounds__(NT, 5) fused_kernel(const float* __restrict__ img,
                                                      const float* __restrict__ M,
                                                      const float* __restrict__ sig,
                                                      float* __restrict__ out) {
    __shared__ FmVec  fmAB[RS * RSP];      // 16B/px -> single b128 per point
    __shared__ __half fmC[RS * RSP];       // f8
    __shared__ __half dv[DS * DSP];        // 1/sqrt(deg) fp16; 1.0 in OOB slots

    const int tid = threadIdx.x;
    // XCD-plane swizzle: XCD i owns plane i; tiles sequential -> halo reuse in L2/L3.
    const int bg   = blockIdx.x & 7;            // b*G+g
    const int tile = blockIdx.x >> 3;           // 0..255
    const int g    = bg & (Gg - 1);
    const int by0  = (tile >> 4) * TILE;
    const int bx0  = (tile & 15) * TILE;
    const bool border = (by0 == 0) | (by0 == Hh - TILE) | (bx0 == 0) | (bx0 == Ww - TILE);

    const float* imgP = img + (size_t)bg * Ff * Nn;
    const float* sgp  = sig + (size_t)bg * Cc * Nn;
    const float* Mg   = M + g * Ff * Ff;        // block-uniform -> scalar path

    auto LD = [&](int idx) -> FmPt {
        FmPt p;
        FmVec v = fmAB[idx];                     // one ds_read_b128
        p.a0 = v.h[0]; p.a1 = v.h[1]; p.b0 = v.h[2]; p.b1 = v.h[3];
        p.cf = __half2float(fmC[idx]);
        return p;
    };

    auto PROCPT = [&](const float* v, int si, bool inimg) {
        float m[Ff];
        if (inimg) {
            float ss = 0.f;
#pragma unroll
            for (int f = 0; f < Ff; ++f) ss = fmaf(v[f], v[f], ss);
            float inv = rsqrtf(fmaxf(ss, 1e-24f));
#pragma unroll
            for (int vv = 0; vv < Ff; ++vv) {
                float acc = 0.f;
#pragma unroll
                for (int cc = 0; cc < Ff; ++cc) acc = fmaf(v[cc], Mg[cc * Ff + vv], acc);
                m[vv] = acc * inv;
            }
        } else {
#pragma unroll
            for (int f = 0; f < Ff; ++f) m[f] = 0.f;
        }
        FmVec vv;
        vv.h[0] = __floats2half2_rn(m[0], m[1]);
        vv.h[1] = __floats2half2_rn(m[2], m[3]);
        vv.h[2] = __floats2half2_rn(m[4], m[5]);
        vv.h[3] = __floats2half2_rn(m[6], m[7]);
        fmAB[si] = vv;
        fmC[si]  = __float2half_rn(m[8]);
    };

    // ---- Phase 1: fm for 36x36 halo-2 region; x-paired float2 img loads ----
    // 648 pairs; pair i2 -> row r=i2/18, cols cp,cp+1 (cp even -> 8B aligned).
#pragma unroll
    for (int k = 0; k < 3; ++k) {
        const int i2 = tid + k * NT;
        if (i2 < 648) {
            const int r  = (unsigned)i2 / 18;
            const int cp = ((unsigned)i2 % 18) * 2;
            const int gy = by0 - 2 + r, gx = bx0 - 2 + cp;
            const int si = r * RSP + cp;
            float v0[Ff], v1[Ff];
            if (!border) {
                const float* src = imgP + gy * Ww + gx;
#pragma unroll
                for (int f = 0; f < Ff; ++f) {
                    float2 t = *(const float2*)&src[f * Nn];
                    v0[f] = t.x; v1[f] = t.y;
                }
                PROCPT(v0, si, true);
                PROCPT(v1, si + 1, true);
            } else {
                const bool okY = (unsigned)gy < Hh;
                const bool ok0 = okY & ((unsigned)gx < Ww);
                const bool ok1 = okY & ((unsigned)(gx + 1) < Ww);
                const float* src = imgP + gy * Ww + gx;
                if (ok0) {
#pragma unroll
                    for (int f = 0; f < Ff; ++f) v0[f] = src[f * Nn];
                }
                if (ok1) {
#pragma unroll
                    for (int f = 0; f < Ff; ++f) v1[f] = src[f * Nn + 1];
                }
                PROCPT(v0, si, ok0);
                PROCPT(v1, si + 1, ok1);
            }
        }
    }
    __syncthreads();

    // ---- Phase 2a: 2x2 quad per thread: 30 unique dots (6 shared), deg->dinv ----
    const int r2 = tid >> 4, c2 = tid & 15;
    const int gy0 = by0 + 2 * r2, gx0 = bx0 + 2 * c2;
    const int wb  = (2 * r2 + 1) * RSP + (2 * c2 + 1);   // fm idx of window (0,0)

    FmPt w0[4], w1[4], w2[4], w3[4];
#pragma unroll
    for (int ci = 0; ci < 4; ++ci) w0[ci] = LD(wb + ci);
#pragma unroll
    for (int ci = 0; ci < 4; ++ci) w1[ci] = LD(wb + RSP + ci);
#pragma unroll
    for (int ci = 0; ci < 4; ++ci) w2[ci] = LD(wb + 2 * RSP + ci);

    float e0[9], e1[9], e2[9], e3[9];
    // px0 = w1[1]
    e0[0] = ew_of(dotfm(w1[1], w0[0])); e0[1] = ew_of(dotfm(w1[1], w0[1])); e0[2] = ew_of(dotfm(w1[1], w0[2]));
    e0[3] = ew_of(dotfm(w1[1], w1[0])); e0[4] = ew_of(dotfm(w1[1], w1[1])); e0[5] = ew_of(dotfm(w1[1], w1[2]));
    e0[6] = ew_of(dotfm(w1[1], w2[0])); e0[7] = ew_of(dotfm(w1[1], w2[1])); e0[8] = ew_of(dotfm(w1[1], w2[2]));
    // px1 = w1[2]  (shares W-edge with px0)
    e1[0] = ew_of(dotfm(w1[2], w0[1])); e1[1] = ew_of(dotfm(w1[2], w0[2])); e1[2] = ew_of(dotfm(w1[2], w0[3]));
    e1[3] = e0[5];                      e1[4] = ew_of(dotfm(w1[2], w1[2])); e1[5] = ew_of(dotfm(w1[2], w1[3]));
    e1[6] = ew_of(dotfm(w1[2], w2[1])); e1[7] = ew_of(dotfm(w1[2], w2[2])); e1[8] = ew_of(dotfm(w1[2], w2[3]));

#pragma unroll
    for (int ci = 0; ci < 4; ++ci) w3[ci] = LD(wb + 3 * RSP + ci);   // w0 now dead

    // px2 = w2[1]  (shares N=e0.S, NE=e1.SW)
    e2[0] = ew_of(dotfm(w2[1], w1[0])); e2[1] = e0[7];                      e2[2] = e1[6];
    e2[3] = ew_of(dotfm(w2[1], w2[0])); e2[4] = ew_of(dotfm(w2[1], w2[1])); e2[5] = ew_of(dotfm(w2[1], w2[2]));
    e2[6] = ew_of(dotfm(w2[1], w3[0])); e2[7] = ew_of(dotfm(w2[1], w3[1])); e2[8] = ew_of(dotfm(w2[1], w3[2]));
    // px3 = w2[2]  (shares NW=e0.SE, N=e1.S, W=e2.E)
    e3[0] = e0[8];                      e3[1] = e1[7];                      e3[2] = ew_of(dotfm(w2[2], w1[3]));
    e3[3] = e2[5];                      e3[4] = ew_of(dotfm(w2[2], w2[2])); e3[5] = ew_of(dotfm(w2[2], w2[3]));
    e3[6] = ew_of(dotfm(w2[2], w3[1])); e3[7] = ew_of(dotfm(w2[2], w3[2])); e3[8] = ew_of(dotfm(w2[2], w3[3]));

    if (border) {   // mask edges leaving the image
#pragma unroll
        for (int j = 0; j < 9; ++j) {
            int dy = j / 3 - 1, dx = j % 3 - 1;
            if (!(((unsigned)(gy0 + dy)     < Hh) & ((unsigned)(gx0 + dx)     < Ww))) e0[j] = 0.f;
            if (!(((unsigned)(gy0 + dy)     < Hh) & ((unsigned)(gx0 + 1 + dx) < Ww))) e1[j] = 0.f;
            if (!(((unsigned)(gy0 + 1 + dy) < Hh) & ((unsigned)(gx0 + dx)     < Ww))) e2[j] = 0.f;
            if (!(((unsigned)(gy0 + 1 + dy) < Hh) & ((unsigned)(gx0 + 1 + dx) < Ww))) e3[j] = 0.f;
        }
    }

    float deg0 = 0.f, deg1 = 0.f, deg2 = 0.f, deg3 = 0.f;
#pragma unroll
    for (int j = 0; j < 9; ++j) { deg0 += e0[j]; deg1 += e1[j]; deg2 += e2[j]; deg3 += e3[j]; }
    const float dp0 = 1.0f / sqrtf(deg0);
    const float dp1 = 1.0f / sqrtf(deg1);
    const float dp2 = 1.0f / sqrtf(deg2);
    const float dp3 = 1.0f / sqrtf(deg3);
    {
        const int db = (2 * r2 + 1) * DSP + (2 * c2 + 1);
        dv[db]           = __float2half_rn(dp0);
        dv[db + 1]       = __float2half_rn(dp1);
        dv[db + DSP]     = __float2half_rn(dp2);
        dv[db + DSP + 1] = __float2half_rn(dp3);
    }

    // pack e -> 18 half2 regs (frees 36 fp32 regs for the sig prefetch below)
    __half2 ep01[9], ep23[9];
#pragma unroll
    for (int j = 0; j < 9; ++j) {
        ep01[j] = __floats2half2_rn(e0[j], e1[j]);
        ep23[j] = __floats2half2_rn(e2[j], e3[j]);
    }

    // ---- Hoisted phase-3 sig prefetch: in flight across ring + barrier ----
    int ry[4];
#pragma unroll
    for (int i = 0; i < 4; ++i) ry[i] = min(max(gy0 - 1 + i, 0), Hh - 1) * Ww;
    const int cxm = max(gx0 - 1, 0), cxp = min(gx0 + 2, Ww - 1);
    float s0[16], s1[16], s2[16];
#pragma unroll
    for (int ch = 0; ch < Cc; ++ch) {
        float* sv = (ch == 0) ? s0 : (ch == 1) ? s1 : s2;
        const float* sc = sgp + (size_t)ch * Nn;
#pragma unroll
        for (int i = 0; i < 4; ++i) {
            float2 mid = *(const float2*)&sc[ry[i] + gx0];   // cols 0,1 (aligned, in-image)
            sv[4 * i]     = sc[ry[i] + cxm];
            sv[4 * i + 1] = mid.x;
            sv[4 * i + 2] = mid.y;
            sv[4 * i + 3] = sc[ry[i] + cxp];
        }
    }

    // ---- Phase 2b: halo ring (132 px): deg only; OOB slots -> 1.0 ----
    if (tid < 132) {
        int r, c;
        if (tid < 34)       { r = 0;        c = tid;       }
        else if (tid < 68)  { r = 33;       c = tid - 34;  }
        else if (tid < 100) { r = tid - 67; c = 0;         }
        else                { r = tid - 99; c = 33;        }
        int gy = by0 - 1 + r, gx = bx0 - 1 + c;
        float d = 1.0f;
        if ((unsigned)gy < Hh && (unsigned)gx < Ww) {
            int fi = (r + 1) * RSP + (c + 1);
            FmPt a = LD(fi);
            float deg = 0.f;
#pragma unroll
            for (int j = 0; j < 9; ++j) {
                int dy = j / 3 - 1, dx = j % 3 - 1;
                FmPt q = LD(fi + dy * RSP + dx);
                float e = ew_of(dotfm(a, q));
                bool valid = ((unsigned)(gy + dy) < Hh) & ((unsigned)(gx + dx) < Ww);
                deg += valid ? e : 0.f;
            }
            d = 1.0f / sqrtf(deg);
        }
        dv[r * DSP + c] = __float2half_rn(d);
    }
    __syncthreads();

    // ---- Phase 3: unpack e, weight by dv window, aggregate hoisted sig ----
    float dvf[16];
    {
        const int db = 2 * r2 * DSP + 2 * c2;    // window (0,0) in dv coords
#pragma unroll
        for (int k = 0; k < 16; ++k)
            dvf[k] = __half2float(dv[db + (k >> 2) * DSP + (k & 3)]);
    }
    float we0[9], we1[9], we2[9], we3[9];
#pragma unroll
    for (int j = 0; j < 9; ++j) {
        const int k0 = (j / 3) * 4 + (j % 3);
        we0[j] = dp0 * __low2float(ep01[j])  * dvf[k0];
        we1[j] = dp1 * __high2float(ep01[j]) * dvf[k0 + 1];
        we2[j] = dp2 * __low2float(ep23[j])  * dvf[k0 + 4];
        we3[j] = dp3 * __high2float(ep23[j]) * dvf[k0 + 5];
    }

    float* o = out + (size_t)bg * Cc * Nn;
    const int p = gy0 * Ww + gx0;
    {
        float a0 = 0.f, a1 = 0.f, a2 = 0.f, a3 = 0.f;
        float b0 = 0.f, b1 = 0.f, b2 = 0.f, b3 = 0.f;
#pragma unroll
        for (int j = 0; j < 9; ++j) {
            const int k0 = (j / 3) * 4 + (j % 3);
            a0 = fmaf(we0[j], s0[k0],     a0);
            a1 = fmaf(we1[j], s0[k0 + 1], a1);
            a2 = fmaf(we2[j], s0[k0 + 4], a2);
            a3 = fmaf(we3[j], s0[k0 + 5], a3);
            b0 = fmaf(we0[j], s1[k0],     b0);
            b1 = fmaf(we1[j], s1[k0 + 1], b1);
            b2 = fmaf(we2[j], s1[k0 + 4], b2);
            b3 = fmaf(we3[j], s1[k0 + 5], b3);
        }
        *(float2*)&o[p]           = make_float2(s0[5] - a0, s0[6]  - a1);
        *(float2*)&o[p + Ww]      = make_float2(s0[9] - a2, s0[10] - a3);
        *(float2*)&o[Nn + p]      = make_float2(s1[5] - b0, s1[6]  - b1);
        *(float2*)&o[Nn + p + Ww] = make_float2(s1[9] - b2, s1[10] - b3);
    }
    {
        float c0 = 0.f, c1 = 0.f, c2v = 0.f, c3 = 0.f;
#pragma unroll
        for (int j = 0; j < 9; ++j) {
            const int k0 = (j / 3) * 4 + (j % 3);
            c0  = fmaf(we0[j], s2[k0],     c0);
            c1  = fmaf(we1[j], s2[k0 + 1], c1);
            c2v = fmaf(we2[j], s2[k0 + 4], c2v);
            c3  = fmaf(we3[j], s2[k0 + 5], c3);
        }
        *(float2*)&o[2 * Nn + p]      = make_float2(s2[5] - c0,  s2[6]  - c1);
        *(float2*)&o[2 * Nn + p + Ww] = make_float2(s2[9] - c2v, s2[10] - c3);
    }
}

extern "C" void kernel_launch(void* const* d_in, const int* in_sizes, int n_in,
                              void* d_out, int out_size, void* d_ws, size_t ws_size,
                              hipStream_t stream) {
    const float* img = (const float*)d_in[0];   // (B,G,F,H,W)
    const float* sig = (const float*)d_in[1];   // (B,G,C,H,W)
    const float* M   = (const float*)d_in[2];   // (G,F,F)
    float* out = (float*)d_out;

    fused_kernel<<<dim3(256 * Bb * Gg), NT, 0, stream>>>(img, M, sig, out);
}

// Round 17
// 41.153 us; speedup vs baseline: 1.2837x; 1.2837x over previous
//
#include <hip/hip_runtime.h>
#include <hip/hip_fp16.h>

#define Hh 512
#define Ww 512
#define Bb 2
#define Gg 4
#define Ff 9
#define Cc 3
#define Nn (Hh*Ww)

#define TILE 32
#define RS 36          // fM region: tile + halo 2
#define RSP 37         // padded row stride (bank-rotate, odd)
#define DS 34          // dinv region: tile + halo 1
#define DSP 36         // dv row stride (EVEN -> aligned half2 pair reads)
#define NT 256         // each thread owns a 2x2 pixel quad

typedef float f32x2 __attribute__((ext_vector_type(2)));

struct Pk { unsigned a, b; float cf; };   // 8 x fp8 e4m3 + f8 fp32 (one b128 in LDS)

__device__ __forceinline__ void dec8(const Pk& p, float* v) {
    f32x2 p01 = __builtin_amdgcn_cvt_pk_f32_fp8(p.a, false);
    f32x2 p23 = __builtin_amdgcn_cvt_pk_f32_fp8(p.a, true);
    f32x2 p45 = __builtin_amdgcn_cvt_pk_f32_fp8(p.b, false);
    f32x2 p67 = __builtin_amdgcn_cvt_pk_f32_fp8(p.b, true);
    v[0] = p01[0]; v[1] = p01[1]; v[2] = p23[0]; v[3] = p23[1];
    v[4] = p45[0]; v[5] = p45[1]; v[6] = p67[0]; v[7] = p67[1];
}

// center (decoded) . packed neighbor
__device__ __forceinline__ float dotC(const float* v, float vcf, const Pk& q) {
    f32x2 q01 = __builtin_amdgcn_cvt_pk_f32_fp8(q.a, false);
    f32x2 q23 = __builtin_amdgcn_cvt_pk_f32_fp8(q.a, true);
    f32x2 q45 = __builtin_amdgcn_cvt_pk_f32_fp8(q.b, false);
    f32x2 q67 = __builtin_amdgcn_cvt_pk_f32_fp8(q.b, true);
    float s = v[0] * q01[0];
    s = fmaf(v[1], q01[1], s);
    s = fmaf(v[2], q23[0], s);
    s = fmaf(v[3], q23[1], s);
    s = fmaf(v[4], q45[0], s);
    s = fmaf(v[5], q45[1], s);
    s = fmaf(v[6], q67[0], s);
    s = fmaf(v[7], q67[1], s);
    s = fmaf(vcf, q.cf, s);
    return s;
}

// |sim| <= 0.27 << 10 -> reference clamp never fires; skip it.
__device__ __forceinline__ float ew_of(float s) { return __expf(s); }

__global__ void __launch_bounds__(NT, 5) fused_kernel(const float* __restrict__ img,
                                                      const float* __restrict__ M,
                                                      const float* __restrict__ sig,
                                                      float* __restrict__ out) {
    __shared__ uint4  fm[RS * RSP];        // one b128 per point (fp8 x8 + fp32 f8)
    __shared__ __half dv[DS * DSP];        // 1/sqrt(deg) fp16; 1.0 in OOB slots

    const int tid = threadIdx.x;
    // XCD-plane swizzle: XCD i owns plane i; tiles sequential -> halo reuse in L2/L3.
    const int bg   = blockIdx.x & 7;            // b*G+g
    const int tile = blockIdx.x >> 3;           // 0..255
    const int g    = bg & (Gg - 1);
    const int by0  = (tile >> 4) * TILE;
    const int bx0  = (tile & 15) * TILE;
    const bool border = (by0 == 0) | (by0 == Hh - TILE) | (bx0 == 0) | (bx0 == Ww - TILE);

    const float* imgP = img + (size_t)bg * Ff * Nn;
    const float* sgp  = sig + (size_t)bg * Cc * Nn;
    const float* Mg   = M + g * Ff * Ff;        // block-uniform -> scalar path

    auto LDP = [&](int idx) -> Pk {
        uint4 t = fm[idx];                       // one ds_read_b128
        Pk p; p.a = t.x; p.b = t.y; p.cf = __uint_as_float(t.z);
        return p;
    };

    auto PROCPT = [&](const float* v, int si, bool inimg) {
        float m[Ff];
        if (inimg) {
            float ss = 0.f;
#pragma unroll
            for (int f = 0; f < Ff; ++f) ss = fmaf(v[f], v[f], ss);
            float inv = rsqrtf(fmaxf(ss, 1e-24f));
#pragma unroll
            for (int vv = 0; vv < Ff; ++vv) {
                float acc = 0.f;
#pragma unroll
                for (int cc = 0; cc < Ff; ++cc) acc = fmaf(v[cc], Mg[cc * Ff + vv], acc);
                m[vv] = acc * inv;
            }
        } else {
#pragma unroll
            for (int f = 0; f < Ff; ++f) m[f] = 0.f;
        }
        int A = __builtin_amdgcn_cvt_pk_fp8_f32(m[0], m[1], 0, false);
        A     = __builtin_amdgcn_cvt_pk_fp8_f32(m[2], m[3], A, true);
        int B = __builtin_amdgcn_cvt_pk_fp8_f32(m[4], m[5], 0, false);
        B     = __builtin_amdgcn_cvt_pk_fp8_f32(m[6], m[7], B, true);
        fm[si] = make_uint4((unsigned)A, (unsigned)B, __float_as_uint(m[8]), 0u);
    };

    // ---- Phase 1: fm for 36x36 halo-2 region; x-paired float2 img loads ----
#pragma unroll
    for (int k = 0; k < 3; ++k) {
        const int i2 = tid + k * NT;
        if (i2 < 648) {
            const int r  = (unsigned)i2 / 18;
            const int cp = ((unsigned)i2 % 18) * 2;
            const int gy = by0 - 2 + r, gx = bx0 - 2 + cp;
            const int si = r * RSP + cp;
            float v0[Ff], v1[Ff];
            if (!border) {
                const float* src = imgP + gy * Ww + gx;
#pragma unroll
                for (int f = 0; f < Ff; ++f) {
                    float2 t = *(const float2*)&src[f * Nn];
                    v0[f] = t.x; v1[f] = t.y;
                }
                PROCPT(v0, si, true);
                PROCPT(v1, si + 1, true);
            } else {
                const bool okY = (unsigned)gy < Hh;
                const bool ok0 = okY & ((unsigned)gx < Ww);
                const bool ok1 = okY & ((unsigned)(gx + 1) < Ww);
                const float* src = imgP + gy * Ww + gx;
                if (ok0) {
#pragma unroll
                    for (int f = 0; f < Ff; ++f) v0[f] = src[f * Nn];
                }
                if (ok1) {
#pragma unroll
                    for (int f = 0; f < Ff; ++f) v1[f] = src[f * Nn + 1];
                }
                PROCPT(v0, si, ok0);
                PROCPT(v1, si + 1, ok1);
            }
        }
    }
    __syncthreads();

    // ---- Phase 2a: 2x2 quad per thread: 30 unique dots (6 shared), deg->dinv ----
    const int r2 = tid >> 4, c2 = tid & 15;
    const int gy0 = by0 + 2 * r2, gx0 = bx0 + 2 * c2;
    const int wb  = (2 * r2 + 1) * RSP + (2 * c2 + 1);   // fm idx of window (0,0)

    Pk w0[4], w1[4], w2[4], w3[4];
#pragma unroll
    for (int ci = 0; ci < 4; ++ci) w0[ci] = LDP(wb + ci);
#pragma unroll
    for (int ci = 0; ci < 4; ++ci) w1[ci] = LDP(wb + RSP + ci);
#pragma unroll
    for (int ci = 0; ci < 4; ++ci) w2[ci] = LDP(wb + 2 * RSP + ci);

    // decode the 4 quad centers once
    float A0v[8], A1v[8], A2v[8], A3v[8];
    float A0c, A1c, A2c, A3c;
    dec8(w1[1], A0v); A0c = w1[1].cf;
    dec8(w1[2], A1v); A1c = w1[2].cf;

    float e0[9], e1[9], e2[9], e3[9];
    // px0 = w1[1]
    e0[0] = ew_of(dotC(A0v, A0c, w0[0])); e0[1] = ew_of(dotC(A0v, A0c, w0[1])); e0[2] = ew_of(dotC(A0v, A0c, w0[2]));
    e0[3] = ew_of(dotC(A0v, A0c, w1[0])); e0[4] = ew_of(dotC(A0v, A0c, w1[1])); e0[5] = ew_of(dotC(A0v, A0c, w1[2]));
    e0[6] = ew_of(dotC(A0v, A0c, w2[0])); e0[7] = ew_of(dotC(A0v, A0c, w2[1])); e0[8] = ew_of(dotC(A0v, A0c, w2[2]));
    // px1 = w1[2]  (shares W-edge with px0)
    e1[0] = ew_of(dotC(A1v, A1c, w0[1])); e1[1] = ew_of(dotC(A1v, A1c, w0[2])); e1[2] = ew_of(dotC(A1v, A1c, w0[3]));
    e1[3] = e0[5];                        e1[4] = ew_of(dotC(A1v, A1c, w1[2])); e1[5] = ew_of(dotC(A1v, A1c, w1[3]));
    e1[6] = ew_of(dotC(A1v, A1c, w2[1])); e1[7] = ew_of(dotC(A1v, A1c, w2[2])); e1[8] = ew_of(dotC(A1v, A1c, w2[3]));

#pragma unroll
    for (int ci = 0; ci < 4; ++ci) w3[ci] = LDP(wb + 3 * RSP + ci);   // w0 now dead
    dec8(w2[1], A2v); A2c = w2[1].cf;
    dec8(w2[2], A3v); A3c = w2[2].cf;

    // px2 = w2[1]  (shares N=e0.S, NE=e1.SW)
    e2[0] = ew_of(dotC(A2v, A2c, w1[0])); e2[1] = e0[7];                        e2[2] = e1[6];
    e2[3] = ew_of(dotC(A2v, A2c, w2[0])); e2[4] = ew_of(dotC(A2v, A2c, w2[1])); e2[5] = ew_of(dotC(A2v, A2c, w2[2]));
    e2[6] = ew_of(dotC(A2v, A2c, w3[0])); e2[7] = ew_of(dotC(A2v, A2c, w3[1])); e2[8] = ew_of(dotC(A2v, A2c, w3[2]));
    // px3 = w2[2]  (shares NW=e0.SE, N=e1.S, W=e2.E)
    e3[0] = e0[8];                        e3[1] = e1[7];                        e3[2] = ew_of(dotC(A3v, A3c, w1[3]));
    e3[3] = e2[5];                        e3[4] = ew_of(dotC(A3v, A3c, w2[2])); e3[5] = ew_of(dotC(A3v, A3c, w2[3]));
    e3[6] = ew_of(dotC(A3v, A3c, w3[1])); e3[7] = ew_of(dotC(A3v, A3c, w3[2])); e3[8] = ew_of(dotC(A3v, A3c, w3[3]));

    if (border) {   // mask edges leaving the image
#pragma unroll
        for (int j = 0; j < 9; ++j) {
            int dy = j / 3 - 1, dx = j % 3 - 1;
            if (!(((unsigned)(gy0 + dy)     < Hh) & ((unsigned)(gx0 + dx)     < Ww))) e0[j] = 0.f;
            if (!(((unsigned)(gy0 + dy)     < Hh) & ((unsigned)(gx0 + 1 + dx) < Ww))) e1[j] = 0.f;
            if (!(((unsigned)(gy0 + 1 + dy) < Hh) & ((unsigned)(gx0 + dx)     < Ww))) e2[j] = 0.f;
            if (!(((unsigned)(gy0 + 1 + dy) < Hh) & ((unsigned)(gx0 + 1 + dx) < Ww))) e3[j] = 0.f;
        }
    }

    float deg0 = 0.f, deg1 = 0.f, deg2 = 0.f, deg3 = 0.f;
#pragma unroll
    for (int j = 0; j < 9; ++j) { deg0 += e0[j]; deg1 += e1[j]; deg2 += e2[j]; deg3 += e3[j]; }
    const float dp0 = 1.0f / sqrtf(deg0);
    const float dp1 = 1.0f / sqrtf(deg1);
    const float dp2 = 1.0f / sqrtf(deg2);
    const float dp3 = 1.0f / sqrtf(deg3);
    {
        const int db = (2 * r2 + 1) * DSP + (2 * c2 + 1);
        dv[db]           = __float2half_rn(dp0);
        dv[db + 1]       = __float2half_rn(dp1);
        dv[db + DSP]     = __float2half_rn(dp2);
        dv[db + DSP + 1] = __float2half_rn(dp3);
    }

    // ---- Phase 2b: halo ring (132 px): deg only; OOB slots -> 1.0 ----
    if (tid < 132) {
        int r, c;
        if (tid < 34)       { r = 0;        c = tid;       }
        else if (tid < 68)  { r = 33;       c = tid - 34;  }
        else if (tid < 100) { r = tid - 67; c = 0;         }
        else                { r = tid - 99; c = 33;        }
        int gy = by0 - 1 + r, gx = bx0 - 1 + c;
        float d = 1.0f;
        if ((unsigned)gy < Hh && (unsigned)gx < Ww) {
            int fi = (r + 1) * RSP + (c + 1);
            Pk a = LDP(fi);
            float av[8]; dec8(a, av);
            float deg = 0.f;
#pragma unroll
            for (int j = 0; j < 9; ++j) {
                int dy = j / 3 - 1, dx = j % 3 - 1;
                Pk q = LDP(fi + dy * RSP + dx);
                float e = ew_of(dotC(av, a.cf, q));
                bool valid = ((unsigned)(gy + dy) < Hh) & ((unsigned)(gx + dx) < Ww);
                deg += valid ? e : 0.f;
            }
            d = 1.0f / sqrtf(deg);
        }
        dv[r * DSP + c] = __float2half_rn(d);
    }
    __syncthreads();

    // ---- Phase 3: sig windows (L2-hot), dv via aligned half2 pairs ----
    int ry[4];
#pragma unroll
    for (int i = 0; i < 4; ++i) ry[i] = min(max(gy0 - 1 + i, 0), Hh - 1) * Ww;
    const int cxm = max(gx0 - 1, 0), cxp = min(gx0 + 2, Ww - 1);

    float s0[16], s1[16];
#pragma unroll
    for (int i = 0; i < 4; ++i) {
        float2 mid = *(const float2*)&sgp[ry[i] + gx0];
        s0[4 * i]     = sgp[ry[i] + cxm];
        s0[4 * i + 1] = mid.x;
        s0[4 * i + 2] = mid.y;
        s0[4 * i + 3] = sgp[ry[i] + cxp];
    }
#pragma unroll
    for (int i = 0; i < 4; ++i) {
        float2 mid = *(const float2*)&sgp[Nn + ry[i] + gx0];
        s1[4 * i]     = sgp[Nn + ry[i] + cxm];
        s1[4 * i + 1] = mid.x;
        s1[4 * i + 2] = mid.y;
        s1[4 * i + 3] = sgp[Nn + ry[i] + cxp];
    }

    float dvf[16];
    {
        const int db = 2 * r2 * DSP + 2 * c2;    // even -> aligned half2 pairs
#pragma unroll
        for (int i = 0; i < 4; ++i) {
            __half2 pa = *(const __half2*)&dv[db + i * DSP];
            __half2 pb = *(const __half2*)&dv[db + i * DSP + 2];
            dvf[4 * i]     = __low2float(pa);
            dvf[4 * i + 1] = __high2float(pa);
            dvf[4 * i + 2] = __low2float(pb);
            dvf[4 * i + 3] = __high2float(pb);
        }
    }
#pragma unroll
    for (int j = 0; j < 9; ++j) {
        const int k0 = (j / 3) * 4 + (j % 3);
        e0[j] = dp0 * e0[j] * dvf[k0];
        e1[j] = dp1 * e1[j] * dvf[k0 + 1];
        e2[j] = dp2 * e2[j] * dvf[k0 + 4];
        e3[j] = dp3 * e3[j] * dvf[k0 + 5];
    }

    float s2[16];
#pragma unroll
    for (int i = 0; i < 4; ++i) {
        float2 mid = *(const float2*)&sgp[2 * Nn + ry[i] + gx0];
        s2[4 * i]     = sgp[2 * Nn + ry[i] + cxm];
        s2[4 * i + 1] = mid.x;
        s2[4 * i + 2] = mid.y;
        s2[4 * i + 3] = sgp[2 * Nn + ry[i] + cxp];
    }

    float* o = out + (size_t)bg * Cc * Nn;
    const int p = gy0 * Ww + gx0;
    {
        float a0 = 0.f, a1 = 0.f, a2 = 0.f, a3 = 0.f;
        float b0 = 0.f, b1 = 0.f, b2 = 0.f, b3 = 0.f;
#pragma unroll
        for (int j = 0; j < 9; ++j) {
            const int k0 = (j / 3) * 4 + (j % 3);
            a0 = fmaf(e0[j], s0[k0],     a0);
            a1 = fmaf(e1[j], s0[k0 + 1], a1);
            a2 = fmaf(e2[j], s0[k0 + 4], a2);
            a3 = fmaf(e3[j], s0[k0 + 5], a3);
            b0 = fmaf(e0[j], s1[k0],     b0);
            b1 = fmaf(e1[j], s1[k0 + 1], b1);
            b2 = fmaf(e2[j], s1[k0 + 4], b2);
            b3 = fmaf(e3[j], s1[k0 + 5], b3);
        }
        *(float2*)&o[p]           = make_float2(s0[5] - a0, s0[6]  - a1);
        *(float2*)&o[p + Ww]      = make_float2(s0[9] - a2, s0[10] - a3);
        *(float2*)&o[Nn + p]      = make_float2(s1[5] - b0, s1[6]  - b1);
        *(float2*)&o[Nn + p + Ww] = make_float2(s1[9] - b2, s1[10] - b3);
    }
    {
        float c0 = 0.f, c1 = 0.f, c2v = 0.f, c3 = 0.f;
#pragma unroll
        for (int j = 0; j < 9; ++j) {
            const int k0 = (j / 3) * 4 + (j % 3);
            c0  = fmaf(e0[j], s2[k0],     c0);
            c1  = fmaf(e1[j], s2[k0 + 1], c1);
            c2v = fmaf(e2[j], s2[k0 + 4], c2v);
            c3  = fmaf(e3[j], s2[k0 + 5], c3);
        }
        *(float2*)&o[2 * Nn + p]      = make_float2(s2[5] - c0,  s2[6]  - c1);
        *(float2*)&o[2 * Nn + p + Ww] = make_float2(s2[9] - c2v, s2[10] - c3);
    }
}

extern "C" void kernel_launch(void* const* d_in, const int* in_sizes, int n_in,
                              void* d_out, int out_size, void* d_ws, size_t ws_size,
                              hipStream_t stream) {
    const float* img = (const float*)d_in[0];   // (B,G,F,H,W)
    const float* sig = (const float*)d_in[1];   // (B,G,C,H,W)
    const float* M   = (const float*)d_in[2];   // (G,F,F)
    float* out = (float*)d_out;

    fused_kernel<<<dim3(256 * Bb * Gg), NT, 0, stream>>>(img, M, sig, out);
}

// Round 18
// 38.412 us; speedup vs baseline: 1.3753x; 1.0714x over previous
//
#include <hip/hip_runtime.h>
#include <hip/hip_fp16.h>

#define Hh 512
#define Ww 512
#define Bb 2
#define Gg 4
#define Ff 9
#define Cc 3
#define Nn (Hh*Ww)

#define TILE 32
#define RS 36          // fM region: tile + halo 2
#define RSP 37         // padded row stride (bank-rotate)
#define DS 34          // dinv region: tile + halo 1
#define DSP 36         // dv row stride (EVEN -> aligned half2 pair reads)
#define NT 256         // each thread owns a 2x2 pixel quad

struct __align__(16) FmVec { __half2 h[4]; };   // f0..f7 -> one ds_read_b128

struct FmPt { __half2 a0, a1, b0, b1; float cf; };

__device__ __forceinline__ float dotfm(const FmPt& p, const FmPt& q) {
    __half2 acc = __hmul2(p.a0, q.a0);
    acc = __hfma2(p.a1, q.a1, acc);
    acc = __hfma2(p.b0, q.b0, acc);
    acc = __hfma2(p.b1, q.b1, acc);
    return __low2float(acc) + __high2float(acc) + p.cf * q.cf;
}

// |sim| <= |fM_p||fM_q| ~= 0.27 << 10 -> reference clamp never fires; skip it.
__device__ __forceinline__ float ew_of(float s) { return __expf(s); }

__global__ void __launch_bounds__(NT, 4) fused_kernel(const float* __restrict__ img,
                                                      const float* __restrict__ M,
                                                      const float* __restrict__ sig,
                                                      float* __restrict__ out) {
    __shared__ FmVec  fmAB[RS * RSP];      // 16B/px -> single b128 per point
    __shared__ __half fmC[RS * RSP];       // f8
    __shared__ __half dv[DS * DSP];        // 1/sqrt(deg) fp16; 1.0 in OOB slots

    const int tid = threadIdx.x;
    // XCD-plane swizzle: XCD i owns plane i; tiles sequential -> halo reuse in L2/L3.
    const int bg   = blockIdx.x & 7;            // b*G+g
    const int tile = blockIdx.x >> 3;           // 0..255
    const int g    = bg & (Gg - 1);
    const int by0  = (tile >> 4) * TILE;
    const int bx0  = (tile & 15) * TILE;
    const bool border = (by0 == 0) | (by0 == Hh - TILE) | (bx0 == 0) | (bx0 == Ww - TILE);

    const float* imgP = img + (size_t)bg * Ff * Nn;
    const float* sgp  = sig + (size_t)bg * Cc * Nn;
    const float* Mg   = M + g * Ff * Ff;        // block-uniform -> scalar path

    auto LD = [&](int idx) -> FmPt {
        FmPt p;
        FmVec v = fmAB[idx];                     // one ds_read_b128
        p.a0 = v.h[0]; p.a1 = v.h[1]; p.b0 = v.h[2]; p.b1 = v.h[3];
        p.cf = __half2float(fmC[idx]);
        return p;
    };

    auto PROCPT = [&](const float* v, int si, bool inimg) {
        float m[Ff];
        if (inimg) {
            float ss = 0.f;
#pragma unroll
            for (int f = 0; f < Ff; ++f) ss = fmaf(v[f], v[f], ss);
            float inv = rsqrtf(fmaxf(ss, 1e-24f));
#pragma unroll
            for (int vv = 0; vv < Ff; ++vv) {
                float acc = 0.f;
#pragma unroll
                for (int cc = 0; cc < Ff; ++cc) acc = fmaf(v[cc], Mg[cc * Ff + vv], acc);
                m[vv] = acc * inv;
            }
        } else {
#pragma unroll
            for (int f = 0; f < Ff; ++f) m[f] = 0.f;
        }
        FmVec vv;
        vv.h[0] = __floats2half2_rn(m[0], m[1]);
        vv.h[1] = __floats2half2_rn(m[2], m[3]);
        vv.h[2] = __floats2half2_rn(m[4], m[5]);
        vv.h[3] = __floats2half2_rn(m[6], m[7]);
        fmAB[si] = vv;
        fmC[si]  = __float2half_rn(m[8]);
    };

    // ---- Phase 1: fm for 36x36 halo-2 region; x-paired float2 img loads ----
#pragma unroll
    for (int k = 0; k < 3; ++k) {
        const int i2 = tid + k * NT;
        if (i2 < 648) {
            const int r  = (unsigned)i2 / 18;
            const int cp = ((unsigned)i2 % 18) * 2;
            const int gy = by0 - 2 + r, gx = bx0 - 2 + cp;
            const int si = r * RSP + cp;
            float v0[Ff], v1[Ff];
            if (!border) {
                const float* src = imgP + gy * Ww + gx;
#pragma unroll
                for (int f = 0; f < Ff; ++f) {
                    float2 t = *(const float2*)&src[f * Nn];
                    v0[f] = t.x; v1[f] = t.y;
                }
                PROCPT(v0, si, true);
                PROCPT(v1, si + 1, true);
            } else {
                const bool okY = (unsigned)gy < Hh;
                const bool ok0 = okY & ((unsigned)gx < Ww);
                const bool ok1 = okY & ((unsigned)(gx + 1) < Ww);
                const float* src = imgP + gy * Ww + gx;
                if (ok0) {
#pragma unroll
                    for (int f = 0; f < Ff; ++f) v0[f] = src[f * Nn];
                }
                if (ok1) {
#pragma unroll
                    for (int f = 0; f < Ff; ++f) v1[f] = src[f * Nn + 1];
                }
                PROCPT(v0, si, ok0);
                PROCPT(v1, si + 1, ok1);
            }
        }
    }
    __syncthreads();

    const int r2 = tid >> 4, c2 = tid & 15;
    const int gy0 = by0 + 2 * r2, gx0 = bx0 + 2 * c2;
    const int wb  = (2 * r2 + 1) * RSP + (2 * c2 + 1);   // fm idx of window (0,0)

    // ---- Hoisted sig prefetch (c0,c1): in flight across ALL of phase 2 ----
    int ry[4];
#pragma unroll
    for (int i = 0; i < 4; ++i) ry[i] = min(max(gy0 - 1 + i, 0), Hh - 1) * Ww;
    const int cxm = max(gx0 - 1, 0), cxp = min(gx0 + 2, Ww - 1);
    float s0[16], s1[16];
#pragma unroll
    for (int i = 0; i < 4; ++i) {
        float2 mid = *(const float2*)&sgp[ry[i] + gx0];
        s0[4 * i]     = sgp[ry[i] + cxm];
        s0[4 * i + 1] = mid.x;
        s0[4 * i + 2] = mid.y;
        s0[4 * i + 3] = sgp[ry[i] + cxp];
    }
#pragma unroll
    for (int i = 0; i < 4; ++i) {
        float2 mid = *(const float2*)&sgp[Nn + ry[i] + gx0];
        s1[4 * i]     = sgp[Nn + ry[i] + cxm];
        s1[4 * i + 1] = mid.x;
        s1[4 * i + 2] = mid.y;
        s1[4 * i + 3] = sgp[Nn + ry[i] + cxp];
    }

    // ---- Phase 2a: 2x2 quad per thread: 30 unique dots (6 shared), deg->dinv ----
    FmPt w0[4], w1[4], w2[4], w3[4];
#pragma unroll
    for (int ci = 0; ci < 4; ++ci) w0[ci] = LD(wb + ci);
#pragma unroll
    for (int ci = 0; ci < 4; ++ci) w1[ci] = LD(wb + RSP + ci);
#pragma unroll
    for (int ci = 0; ci < 4; ++ci) w2[ci] = LD(wb + 2 * RSP + ci);

    float e0[9], e1[9], e2[9], e3[9];
    // px0 = w1[1]
    e0[0] = ew_of(dotfm(w1[1], w0[0])); e0[1] = ew_of(dotfm(w1[1], w0[1])); e0[2] = ew_of(dotfm(w1[1], w0[2]));
    e0[3] = ew_of(dotfm(w1[1], w1[0])); e0[4] = ew_of(dotfm(w1[1], w1[1])); e0[5] = ew_of(dotfm(w1[1], w1[2]));
    e0[6] = ew_of(dotfm(w1[1], w2[0])); e0[7] = ew_of(dotfm(w1[1], w2[1])); e0[8] = ew_of(dotfm(w1[1], w2[2]));
    // px1 = w1[2]  (shares W-edge with px0)
    e1[0] = ew_of(dotfm(w1[2], w0[1])); e1[1] = ew_of(dotfm(w1[2], w0[2])); e1[2] = ew_of(dotfm(w1[2], w0[3]));
    e1[3] = e0[5];                      e1[4] = ew_of(dotfm(w1[2], w1[2])); e1[5] = ew_of(dotfm(w1[2], w1[3]));
    e1[6] = ew_of(dotfm(w1[2], w2[1])); e1[7] = ew_of(dotfm(w1[2], w2[2])); e1[8] = ew_of(dotfm(w1[2], w2[3]));

#pragma unroll
    for (int ci = 0; ci < 4; ++ci) w3[ci] = LD(wb + 3 * RSP + ci);   // w0 now dead

    // px2 = w2[1]  (shares N=e0.S, NE=e1.SW)
    e2[0] = ew_of(dotfm(w2[1], w1[0])); e2[1] = e0[7];                      e2[2] = e1[6];
    e2[3] = ew_of(dotfm(w2[1], w2[0])); e2[4] = ew_of(dotfm(w2[1], w2[1])); e2[5] = ew_of(dotfm(w2[1], w2[2]));
    e2[6] = ew_of(dotfm(w2[1], w3[0])); e2[7] = ew_of(dotfm(w2[1], w3[1])); e2[8] = ew_of(dotfm(w2[1], w3[2]));
    // px3 = w2[2]  (shares NW=e0.SE, N=e1.S, W=e2.E)
    e3[0] = e0[8];                      e3[1] = e1[7];                      e3[2] = ew_of(dotfm(w2[2], w1[3]));
    e3[3] = e2[5];                      e3[4] = ew_of(dotfm(w2[2], w2[2])); e3[5] = ew_of(dotfm(w2[2], w2[3]));
    e3[6] = ew_of(dotfm(w2[2], w3[1])); e3[7] = ew_of(dotfm(w2[2], w3[2])); e3[8] = ew_of(dotfm(w2[2], w3[3]));

    if (border) {   // mask edges leaving the image
#pragma unroll
        for (int j = 0; j < 9; ++j) {
            int dy = j / 3 - 1, dx = j % 3 - 1;
            if (!(((unsigned)(gy0 + dy)     < Hh) & ((unsigned)(gx0 + dx)     < Ww))) e0[j] = 0.f;
            if (!(((unsigned)(gy0 + dy)     < Hh) & ((unsigned)(gx0 + 1 + dx) < Ww))) e1[j] = 0.f;
            if (!(((unsigned)(gy0 + 1 + dy) < Hh) & ((unsigned)(gx0 + dx)     < Ww))) e2[j] = 0.f;
            if (!(((unsigned)(gy0 + 1 + dy) < Hh) & ((unsigned)(gx0 + 1 + dx) < Ww))) e3[j] = 0.f;
        }
    }

    float deg0 = 0.f, deg1 = 0.f, deg2 = 0.f, deg3 = 0.f;
#pragma unroll
    for (int j = 0; j < 9; ++j) { deg0 += e0[j]; deg1 += e1[j]; deg2 += e2[j]; deg3 += e3[j]; }
    const float dp0 = 1.0f / sqrtf(deg0);
    const float dp1 = 1.0f / sqrtf(deg1);
    const float dp2 = 1.0f / sqrtf(deg2);
    const float dp3 = 1.0f / sqrtf(deg3);
    {
        const int db = (2 * r2 + 1) * DSP + (2 * c2 + 1);
        dv[db]           = __float2half_rn(dp0);
        dv[db + 1]       = __float2half_rn(dp1);
        dv[db + DSP]     = __float2half_rn(dp2);
        dv[db + DSP + 1] = __float2half_rn(dp3);
    }

    // ---- Phase 2b: halo ring (132 px): deg only; OOB slots -> 1.0 ----
    if (tid < 132) {
        int r, c;
        if (tid < 34)       { r = 0;        c = tid;       }
        else if (tid < 68)  { r = 33;       c = tid - 34;  }
        else if (tid < 100) { r = tid - 67; c = 0;         }
        else                { r = tid - 99; c = 33;        }
        int gy = by0 - 1 + r, gx = bx0 - 1 + c;
        float d = 1.0f;
        if ((unsigned)gy < Hh && (unsigned)gx < Ww) {
            int fi = (r + 1) * RSP + (c + 1);
            FmPt a = LD(fi);
            float deg = 0.f;
#pragma unroll
            for (int j = 0; j < 9; ++j) {
                int dy = j / 3 - 1, dx = j % 3 - 1;
                FmPt q = LD(fi + dy * RSP + dx);
                float e = ew_of(dotfm(a, q));
                bool valid = ((unsigned)(gy + dy) < Hh) & ((unsigned)(gx + dx) < Ww);
                deg += valid ? e : 0.f;
            }
            d = 1.0f / sqrtf(deg);
        }
        dv[r * DSP + c] = __float2half_rn(d);
    }
    __syncthreads();

    // ---- Phase 3: dv via aligned half2 pairs; e -> w; aggregate ----
    float dvf[16];
    {
        const int db = 2 * r2 * DSP + 2 * c2;    // even -> aligned half2 pairs
#pragma unroll
        for (int i = 0; i < 4; ++i) {
            __half2 pa = *(const __half2*)&dv[db + i * DSP];
            __half2 pb = *(const __half2*)&dv[db + i * DSP + 2];
            dvf[4 * i]     = __low2float(pa);
            dvf[4 * i + 1] = __high2float(pa);
            dvf[4 * i + 2] = __low2float(pb);
            dvf[4 * i + 3] = __high2float(pb);
        }
    }
#pragma unroll
    for (int j = 0; j < 9; ++j) {
        const int k0 = (j / 3) * 4 + (j % 3);
        e0[j] = dp0 * e0[j] * dvf[k0];
        e1[j] = dp1 * e1[j] * dvf[k0 + 1];
        e2[j] = dp2 * e2[j] * dvf[k0 + 4];
        e3[j] = dp3 * e3[j] * dvf[k0 + 5];
    }

    // c2 loads issued here -> hidden under the c0/c1 aggregation below
    float s2[16];
#pragma unroll
    for (int i = 0; i < 4; ++i) {
        float2 mid = *(const float2*)&sgp[2 * Nn + ry[i] + gx0];
        s2[4 * i]     = sgp[2 * Nn + ry[i] + cxm];
        s2[4 * i + 1] = mid.x;
        s2[4 * i + 2] = mid.y;
        s2[4 * i + 3] = sgp[2 * Nn + ry[i] + cxp];
    }

    float* o = out + (size_t)bg * Cc * Nn;
    const int p = gy0 * Ww + gx0;
    {
        float a0 = 0.f, a1 = 0.f, a2 = 0.f, a3 = 0.f;
        float b0 = 0.f, b1 = 0.f, b2 = 0.f, b3 = 0.f;
#pragma unroll
        for (int j = 0; j < 9; ++j) {
            const int k0 = (j / 3) * 4 + (j % 3);
            a0 = fmaf(e0[j], s0[k0],     a0);
            a1 = fmaf(e1[j], s0[k0 + 1], a1);
            a2 = fmaf(e2[j], s0[k0 + 4], a2);
            a3 = fmaf(e3[j], s0[k0 + 5], a3);
            b0 = fmaf(e0[j], s1[k0],     b0);
            b1 = fmaf(e1[j], s1[k0 + 1], b1);
            b2 = fmaf(e2[j], s1[k0 + 4], b2);
            b3 = fmaf(e3[j], s1[k0 + 5], b3);
        }
        *(float2*)&o[p]           = make_float2(s0[5] - a0, s0[6]  - a1);
        *(float2*)&o[p + Ww]      = make_float2(s0[9] - a2, s0[10] - a3);
        *(float2*)&o[Nn + p]      = make_float2(s1[5] - b0, s1[6]  - b1);
        *(float2*)&o[Nn + p + Ww] = make_float2(s1[9] - b2, s1[10] - b3);
    }
    {
        float c0 = 0.f, c1 = 0.f, c2v = 0.f, c3 = 0.f;
#pragma unroll
        for (int j = 0; j < 9; ++j) {
            const int k0 = (j / 3) * 4 + (j % 3);
            c0  = fmaf(e0[j], s2[k0],     c0);
            c1  = fmaf(e1[j], s2[k0 + 1], c1);
            c2v = fmaf(e2[j], s2[k0 + 4], c2v);
            c3  = fmaf(e3[j], s2[k0 + 5], c3);
        }
        *(float2*)&o[2 * Nn + p]      = make_float2(s2[5] - c0,  s2[6]  - c1);
        *(float2*)&o[2 * Nn + p + Ww] = make_float2(s2[9] - c2v, s2[10] - c3);
    }
}

extern "C" void kernel_launch(void* const* d_in, const int* in_sizes, int n_in,
                              void* d_out, int out_size, void* d_ws, size_t ws_size,
                              hipStream_t stream) {
    const float* img = (const float*)d_in[0];   // (B,G,F,H,W)
    const float* sig = (const float*)d_in[1];   // (B,G,C,H,W)
    const float* M   = (const float*)d_in[2];   // (G,F,F)
    float* out = (float*)d_out;

    fused_kernel<<<dim3(256 * Bb * Gg), NT, 0, stream>>>(img, M, sig, out);
}

// Round 19
// 35.484 us; speedup vs baseline: 1.4888x; 1.0825x over previous
//
#include <hip/hip_runtime.h>
#include <hip/hip_fp16.h>

#define Hh 512
#define Ww 512
#define Bb 2
#define Gg 4
#define Ff 9
#define Cc 3
#define Nn (Hh*Ww)

#define TILE 32
#define RS 36          // fM region: tile + halo 2
#define RSP 37         // padded row stride (bank-rotate)
#define DS 34          // dinv region: tile + halo 1
#define DSP 36         // dv row stride (EVEN -> aligned half2 pair reads)
#define NT 256         // each thread owns a 2x2 pixel quad

struct __align__(16) FmVec { __half2 h[4]; };   // f0..f7 -> one ds_read_b128

struct FmPt { __half2 a0, a1, b0, b1; float cf; };

__device__ __forceinline__ float dotfm(const FmPt& p, const FmPt& q) {
    __half2 acc = __hmul2(p.a0, q.a0);
    acc = __hfma2(p.a1, q.a1, acc);
    acc = __hfma2(p.b0, q.b0, acc);
    acc = __hfma2(p.b1, q.b1, acc);
    return __low2float(acc) + __high2float(acc) + p.cf * q.cf;
}

// |sim| <= |fM_p||fM_q| ~= 0.27 << 10 -> reference clamp never fires; skip it.
__device__ __forceinline__ float ew_of(float s) { return __expf(s); }

__global__ void __launch_bounds__(NT, 5) fused_kernel(const float* __restrict__ img,
                                                      const float* __restrict__ M,
                                                      const float* __restrict__ sig,
                                                      float* __restrict__ out) {
    __shared__ FmVec  fmAB[RS * RSP];      // 16B/px -> single b128 per point
    __shared__ __half fmC[RS * RSP];       // f8
    __shared__ __half dv[DS * DSP];        // 1/sqrt(deg) fp16; 1.0 in OOB slots

    const int tid = threadIdx.x;
    // XCD-plane swizzle: XCD i owns plane i; tiles sequential -> halo reuse in L2/L3.
    const int bg   = blockIdx.x & 7;            // b*G+g
    const int tile = blockIdx.x >> 3;           // 0..255
    const int g    = bg & (Gg - 1);
    const int by0  = (tile >> 4) * TILE;
    const int bx0  = (tile & 15) * TILE;
    const bool border = (by0 == 0) | (by0 == Hh - TILE) | (bx0 == 0) | (bx0 == Ww - TILE);

    const float* imgP = img + (size_t)bg * Ff * Nn;
    const float* sgp  = sig + (size_t)bg * Cc * Nn;
    const float* Mg   = M + g * Ff * Ff;        // block-uniform -> scalar path

    auto LD = [&](int idx) -> FmPt {
        FmPt p;
        FmVec v = fmAB[idx];                     // one ds_read_b128
        p.a0 = v.h[0]; p.a1 = v.h[1]; p.b0 = v.h[2]; p.b1 = v.h[3];
        p.cf = __half2float(fmC[idx]);
        return p;
    };

    auto PROCPT = [&](const float* v, int si, bool inimg) {
        float m[Ff];
        if (inimg) {
            float ss = 0.f;
#pragma unroll
            for (int f = 0; f < Ff; ++f) ss = fmaf(v[f], v[f], ss);
            float inv = rsqrtf(fmaxf(ss, 1e-24f));
#pragma unroll
            for (int vv = 0; vv < Ff; ++vv) {
                float acc = 0.f;
#pragma unroll
                for (int cc = 0; cc < Ff; ++cc) acc = fmaf(v[cc], Mg[cc * Ff + vv], acc);
                m[vv] = acc * inv;
            }
        } else {
#pragma unroll
            for (int f = 0; f < Ff; ++f) m[f] = 0.f;
        }
        FmVec vv;
        vv.h[0] = __floats2half2_rn(m[0], m[1]);
        vv.h[1] = __floats2half2_rn(m[2], m[3]);
        vv.h[2] = __floats2half2_rn(m[4], m[5]);
        vv.h[3] = __floats2half2_rn(m[6], m[7]);
        fmAB[si] = vv;
        fmC[si]  = __float2half_rn(m[8]);
    };

    // ---- Phase 1: fm for 36x36 halo-2 region ----
    if (!border) {
        // Batched: issue ALL 27 float2 loads (distinct regs), then process 6 points.
        float va[3][2][Ff];
        int   sis[3];
        bool  act[3];
#pragma unroll
        for (int k = 0; k < 3; ++k) {
            const int i2 = tid + k * NT;
            act[k] = i2 < 648;
            if (act[k]) {
                const int r  = (unsigned)i2 / 18;
                const int cp = ((unsigned)i2 % 18) * 2;
                sis[k] = r * RSP + cp;
                const float* src = imgP + (by0 - 2 + r) * Ww + (bx0 - 2 + cp);
#pragma unroll
                for (int f = 0; f < Ff; ++f) {
                    float2 t = *(const float2*)&src[f * Nn];
                    va[k][0][f] = t.x; va[k][1][f] = t.y;
                }
            }
        }
#pragma unroll
        for (int k = 0; k < 3; ++k) {
            if (act[k]) {
                PROCPT(va[k][0], sis[k], true);
                PROCPT(va[k][1], sis[k] + 1, true);
            }
        }
    } else {
        // Border tiles (23%): guarded sequential path.
#pragma unroll
        for (int k = 0; k < 3; ++k) {
            const int i2 = tid + k * NT;
            if (i2 < 648) {
                const int r  = (unsigned)i2 / 18;
                const int cp = ((unsigned)i2 % 18) * 2;
                const int gy = by0 - 2 + r, gx = bx0 - 2 + cp;
                const int si = r * RSP + cp;
                float v0[Ff], v1[Ff];
                const bool okY = (unsigned)gy < Hh;
                const bool ok0 = okY & ((unsigned)gx < Ww);
                const bool ok1 = okY & ((unsigned)(gx + 1) < Ww);
                const float* src = imgP + gy * Ww + gx;
                if (ok0) {
#pragma unroll
                    for (int f = 0; f < Ff; ++f) v0[f] = src[f * Nn];
                }
                if (ok1) {
#pragma unroll
                    for (int f = 0; f < Ff; ++f) v1[f] = src[f * Nn + 1];
                }
                PROCPT(v0, si, ok0);
                PROCPT(v1, si + 1, ok1);
            }
        }
    }
    __syncthreads();

    // ---- Phase 2a: 2x2 quad per thread: 30 unique dots (6 shared), deg->dinv ----
    const int r2 = tid >> 4, c2 = tid & 15;
    const int gy0 = by0 + 2 * r2, gx0 = bx0 + 2 * c2;
    const int wb  = (2 * r2 + 1) * RSP + (2 * c2 + 1);   // fm idx of window (0,0)

    FmPt w0[4], w1[4], w2[4], w3[4];
#pragma unroll
    for (int ci = 0; ci < 4; ++ci) w0[ci] = LD(wb + ci);
#pragma unroll
    for (int ci = 0; ci < 4; ++ci) w1[ci] = LD(wb + RSP + ci);
#pragma unroll
    for (int ci = 0; ci < 4; ++ci) w2[ci] = LD(wb + 2 * RSP + ci);

    float e0[9], e1[9], e2[9], e3[9];
    // px0 = w1[1]
    e0[0] = ew_of(dotfm(w1[1], w0[0])); e0[1] = ew_of(dotfm(w1[1], w0[1])); e0[2] = ew_of(dotfm(w1[1], w0[2]));
    e0[3] = ew_of(dotfm(w1[1], w1[0])); e0[4] = ew_of(dotfm(w1[1], w1[1])); e0[5] = ew_of(dotfm(w1[1], w1[2]));
    e0[6] = ew_of(dotfm(w1[1], w2[0])); e0[7] = ew_of(dotfm(w1[1], w2[1])); e0[8] = ew_of(dotfm(w1[1], w2[2]));
    // px1 = w1[2]  (shares W-edge with px0)
    e1[0] = ew_of(dotfm(w1[2], w0[1])); e1[1] = ew_of(dotfm(w1[2], w0[2])); e1[2] = ew_of(dotfm(w1[2], w0[3]));
    e1[3] = e0[5];                      e1[4] = ew_of(dotfm(w1[2], w1[2])); e1[5] = ew_of(dotfm(w1[2], w1[3]));
    e1[6] = ew_of(dotfm(w1[2], w2[1])); e1[7] = ew_of(dotfm(w1[2], w2[2])); e1[8] = ew_of(dotfm(w1[2], w2[3]));

#pragma unroll
    for (int ci = 0; ci < 4; ++ci) w3[ci] = LD(wb + 3 * RSP + ci);   // w0 now dead

    // px2 = w2[1]  (shares N=e0.S, NE=e1.SW)
    e2[0] = ew_of(dotfm(w2[1], w1[0])); e2[1] = e0[7];                      e2[2] = e1[6];
    e2[3] = ew_of(dotfm(w2[1], w2[0])); e2[4] = ew_of(dotfm(w2[1], w2[1])); e2[5] = ew_of(dotfm(w2[1], w2[2]));
    e2[6] = ew_of(dotfm(w2[1], w3[0])); e2[7] = ew_of(dotfm(w2[1], w3[1])); e2[8] = ew_of(dotfm(w2[1], w3[2]));
    // px3 = w2[2]  (shares NW=e0.SE, N=e1.S, W=e2.E)
    e3[0] = e0[8];                      e3[1] = e1[7];                      e3[2] = ew_of(dotfm(w2[2], w1[3]));
    e3[3] = e2[5];                      e3[4] = ew_of(dotfm(w2[2], w2[2])); e3[5] = ew_of(dotfm(w2[2], w2[3]));
    e3[6] = ew_of(dotfm(w2[2], w3[1])); e3[7] = ew_of(dotfm(w2[2], w3[2])); e3[8] = ew_of(dotfm(w2[2], w3[3]));

    if (border) {   // mask edges leaving the image
#pragma unroll
        for (int j = 0; j < 9; ++j) {
            int dy = j / 3 - 1, dx = j % 3 - 1;
            if (!(((unsigned)(gy0 + dy)     < Hh) & ((unsigned)(gx0 + dx)     < Ww))) e0[j] = 0.f;
            if (!(((unsigned)(gy0 + dy)     < Hh) & ((unsigned)(gx0 + 1 + dx) < Ww))) e1[j] = 0.f;
            if (!(((unsigned)(gy0 + 1 + dy) < Hh) & ((unsigned)(gx0 + dx)     < Ww))) e2[j] = 0.f;
            if (!(((unsigned)(gy0 + 1 + dy) < Hh) & ((unsigned)(gx0 + 1 + dx) < Ww))) e3[j] = 0.f;
        }
    }

    float deg0 = 0.f, deg1 = 0.f, deg2 = 0.f, deg3 = 0.f;
#pragma unroll
    for (int j = 0; j < 9; ++j) { deg0 += e0[j]; deg1 += e1[j]; deg2 += e2[j]; deg3 += e3[j]; }
    const float dp0 = 1.0f / sqrtf(deg0);
    const float dp1 = 1.0f / sqrtf(deg1);
    const float dp2 = 1.0f / sqrtf(deg2);
    const float dp3 = 1.0f / sqrtf(deg3);
    {
        const int db = (2 * r2 + 1) * DSP + (2 * c2 + 1);
        dv[db]           = __float2half_rn(dp0);
        dv[db + 1]       = __float2half_rn(dp1);
        dv[db + DSP]     = __float2half_rn(dp2);
        dv[db + DSP + 1] = __float2half_rn(dp3);
    }

    // ---- Phase 2b: halo ring (132 px): deg only; OOB slots -> 1.0 ----
    if (tid < 132) {
        int r, c;
        if (tid < 34)       { r = 0;        c = tid;       }
        else if (tid < 68)  { r = 33;       c = tid - 34;  }
        else if (tid < 100) { r = tid - 67; c = 0;         }
        else                { r = tid - 99; c = 33;        }
        int gy = by0 - 1 + r, gx = bx0 - 1 + c;
        float d = 1.0f;
        if ((unsigned)gy < Hh && (unsigned)gx < Ww) {
            int fi = (r + 1) * RSP + (c + 1);
            FmPt a = LD(fi);
            float deg = 0.f;
#pragma unroll
            for (int j = 0; j < 9; ++j) {
                int dy = j / 3 - 1, dx = j % 3 - 1;
                FmPt q = LD(fi + dy * RSP + dx);
                float e = ew_of(dotfm(a, q));
                bool valid = ((unsigned)(gy + dy) < Hh) & ((unsigned)(gx + dx) < Ww);
                deg += valid ? e : 0.f;
            }
            d = 1.0f / sqrtf(deg);
        }
        dv[r * DSP + c] = __float2half_rn(d);
    }
    __syncthreads();

    // ---- Phase 3: sig windows (L2-hot); dv via aligned half2 pairs ----
    int ry[4];
#pragma unroll
    for (int i = 0; i < 4; ++i) ry[i] = min(max(gy0 - 1 + i, 0), Hh - 1) * Ww;
    const int cxm = max(gx0 - 1, 0), cxp = min(gx0 + 2, Ww - 1);

    float s0[16], s1[16];
#pragma unroll
    for (int i = 0; i < 4; ++i) {
        float2 mid = *(const float2*)&sgp[ry[i] + gx0];
        s0[4 * i]     = sgp[ry[i] + cxm];
        s0[4 * i + 1] = mid.x;
        s0[4 * i + 2] = mid.y;
        s0[4 * i + 3] = sgp[ry[i] + cxp];
    }
#pragma unroll
    for (int i = 0; i < 4; ++i) {
        float2 mid = *(const float2*)&sgp[Nn + ry[i] + gx0];
        s1[4 * i]     = sgp[Nn + ry[i] + cxm];
        s1[4 * i + 1] = mid.x;
        s1[4 * i + 2] = mid.y;
        s1[4 * i + 3] = sgp[Nn + ry[i] + cxp];
    }

    float dvf[16];
    {
        const int db = 2 * r2 * DSP + 2 * c2;    // even -> aligned half2 pairs
#pragma unroll
        for (int i = 0; i < 4; ++i) {
            __half2 pa = *(const __half2*)&dv[db + i * DSP];
            __half2 pb = *(const __half2*)&dv[db + i * DSP + 2];
            dvf[4 * i]     = __low2float(pa);
            dvf[4 * i + 1] = __high2float(pa);
            dvf[4 * i + 2] = __low2float(pb);
            dvf[4 * i + 3] = __high2float(pb);
        }
    }
#pragma unroll
    for (int j = 0; j < 9; ++j) {
        const int k0 = (j / 3) * 4 + (j % 3);
        e0[j] = dp0 * e0[j] * dvf[k0];
        e1[j] = dp1 * e1[j] * dvf[k0 + 1];
        e2[j] = dp2 * e2[j] * dvf[k0 + 4];
        e3[j] = dp3 * e3[j] * dvf[k0 + 5];
    }

    // c2 loads issued here -> hidden under the c0/c1 aggregation below
    float s2[16];
#pragma unroll
    for (int i = 0; i < 4; ++i) {
        float2 mid = *(const float2*)&sgp[2 * Nn + ry[i] + gx0];
        s2[4 * i]     = sgp[2 * Nn + ry[i] + cxm];
        s2[4 * i + 1] = mid.x;
        s2[4 * i + 2] = mid.y;
        s2[4 * i + 3] = sgp[2 * Nn + ry[i] + cxp];
    }

    float* o = out + (size_t)bg * Cc * Nn;
    const int p = gy0 * Ww + gx0;
    {
        float a0 = 0.f, a1 = 0.f, a2 = 0.f, a3 = 0.f;
        float b0 = 0.f, b1 = 0.f, b2 = 0.f, b3 = 0.f;
#pragma unroll
        for (int j = 0; j < 9; ++j) {
            const int k0 = (j / 3) * 4 + (j % 3);
            a0 = fmaf(e0[j], s0[k0],     a0);
            a1 = fmaf(e1[j], s0[k0 + 1], a1);
            a2 = fmaf(e2[j], s0[k0 + 4], a2);
            a3 = fmaf(e3[j], s0[k0 + 5], a3);
            b0 = fmaf(e0[j], s1[k0],     b0);
            b1 = fmaf(e1[j], s1[k0 + 1], b1);
            b2 = fmaf(e2[j], s1[k0 + 4], b2);
            b3 = fmaf(e3[j], s1[k0 + 5], b3);
        }
        *(float2*)&o[p]           = make_float2(s0[5] - a0, s0[6]  - a1);
        *(float2*)&o[p + Ww]      = make_float2(s0[9] - a2, s0[10] - a3);
        *(float2*)&o[Nn + p]      = make_float2(s1[5] - b0, s1[6]  - b1);
        *(float2*)&o[Nn + p + Ww] = make_float2(s1[9] - b2, s1[10] - b3);
    }
    {
        float c0 = 0.f, c1 = 0.f, c2v = 0.f, c3 = 0.f;
#pragma unroll
        for (int j = 0; j < 9; ++j) {
            const int k0 = (j / 3) * 4 + (j % 3);
            c0  = fmaf(e0[j], s2[k0],     c0);
            c1  = fmaf(e1[j], s2[k0 + 1], c1);
            c2v = fmaf(e2[j], s2[k0 + 4], c2v);
            c3  = fmaf(e3[j], s2[k0 + 5], c3);
        }
        *(float2*)&o[2 * Nn + p]      = make_float2(s2[5] - c0,  s2[6]  - c1);
        *(float2*)&o[2 * Nn + p + Ww] = make_float2(s2[9] - c2v, s2[10] - c3);
    }
}

extern "C" void kernel_launch(void* const* d_in, const int* in_sizes, int n_in,
                              void* d_out, int out_size, void* d_ws, size_t ws_size,
                              hipStream_t stream) {
    const float* img = (const float*)d_in[0];   // (B,G,F,H,W)
    const float* sig = (const float*)d_in[1];   // (B,G,C,H,W)
    const float* M   = (const float*)d_in[2];   // (G,F,F)
    float* out = (float*)d_out;

    fused_kernel<<<dim3(256 * Bb * Gg), NT, 0, stream>>>(img, M, sig, out);
}

// Round 20
// 34.832 us; speedup vs baseline: 1.5166x; 1.0187x over previous
//
#include <hip/hip_runtime.h>
#include <hip/hip_fp16.h>

#define Hh 512
#define Ww 512
#define Bb 2
#define Gg 4
#define Ff 9
#define Cc 3
#define Nn (Hh*Ww)

#define TILE 32
#define RS 36          // fM region: tile + halo 2
#define RSP 37         // padded row stride (bank-rotate)
#define DS 34          // dinv region: tile + halo 1
#define DSP 36         // dv row stride (EVEN -> aligned half2 pair reads)
#define NT 256         // each thread owns a 2x2 pixel quad

struct __align__(16) FmVec { __half2 h[4]; };   // f0..f7 -> one ds_read_b128

struct FmPt { __half2 a0, a1, b0, b1; float cf; };

__device__ __forceinline__ float dotfm(const FmPt& p, const FmPt& q) {
    __half2 acc = __hmul2(p.a0, q.a0);
    acc = __hfma2(p.a1, q.a1, acc);
    acc = __hfma2(p.b0, q.b0, acc);
    acc = __hfma2(p.b1, q.b1, acc);
    return __low2float(acc) + __high2float(acc) + p.cf * q.cf;
}

// |sim| <= |fM_p||fM_q| ~= 0.27 << 10 -> reference clamp never fires; skip it.
__device__ __forceinline__ float ew_of(float s) { return __expf(s); }

__global__ void __launch_bounds__(NT, 5) fused_kernel(const float* __restrict__ img,
                                                      const float* __restrict__ M,
                                                      const float* __restrict__ sig,
                                                      float* __restrict__ out) {
    __shared__ FmVec  fmAB[RS * RSP];      // 16B/px -> single b128 per point
    __shared__ __half fmC[RS * RSP];       // f8
    __shared__ __half dv[DS * DSP];        // 1/sqrt(deg) fp16; 1.0 in OOB slots

    const int tid = threadIdx.x;
    // XCD-plane swizzle: XCD i owns plane i; tiles sequential -> halo reuse in L2/L3.
    const int bg   = blockIdx.x & 7;            // b*G+g
    const int tile = blockIdx.x >> 3;           // 0..255
    const int g    = bg & (Gg - 1);
    const int by0  = (tile >> 4) * TILE;
    const int bx0  = (tile & 15) * TILE;
    const bool border = (by0 == 0) | (by0 == Hh - TILE) | (bx0 == 0) | (bx0 == Ww - TILE);

    const float* imgP = img + (size_t)bg * Ff * Nn;
    const float* sgp  = sig + (size_t)bg * Cc * Nn;
    const float* Mg   = M + g * Ff * Ff;        // block-uniform -> scalar path

    auto LD = [&](int idx) -> FmPt {
        FmPt p;
        FmVec v = fmAB[idx];                     // one ds_read_b128
        p.a0 = v.h[0]; p.a1 = v.h[1]; p.b0 = v.h[2]; p.b1 = v.h[3];
        p.cf = __half2float(fmC[idx]);
        return p;
    };

    auto PROCPT = [&](const float* v, int si, bool inimg) {
        float m[Ff];
        if (inimg) {
            float ss = 0.f;
#pragma unroll
            for (int f = 0; f < Ff; ++f) ss = fmaf(v[f], v[f], ss);
            float inv = rsqrtf(fmaxf(ss, 1e-24f));
#pragma unroll
            for (int vv = 0; vv < Ff; ++vv) {
                float acc = 0.f;
#pragma unroll
                for (int cc = 0; cc < Ff; ++cc) acc = fmaf(v[cc], Mg[cc * Ff + vv], acc);
                m[vv] = acc * inv;
            }
        } else {
#pragma unroll
            for (int f = 0; f < Ff; ++f) m[f] = 0.f;
        }
        FmVec vv;
        vv.h[0] = __floats2half2_rn(m[0], m[1]);
        vv.h[1] = __floats2half2_rn(m[2], m[3]);
        vv.h[2] = __floats2half2_rn(m[4], m[5]);
        vv.h[3] = __floats2half2_rn(m[6], m[7]);
        fmAB[si] = vv;
        fmC[si]  = __float2half_rn(m[8]);
    };

    // ---- Phase 1: fm for 36x36 halo-2 region ----
    if (!border) {
        // Batched: issue ALL 27 float2 loads (distinct regs), then process 6 points.
        float va[3][2][Ff];
        int   sis[3];
        bool  act[3];
#pragma unroll
        for (int k = 0; k < 3; ++k) {
            const int i2 = tid + k * NT;
            act[k] = i2 < 648;
            if (act[k]) {
                const int r  = (unsigned)i2 / 18;
                const int cp = ((unsigned)i2 % 18) * 2;
                sis[k] = r * RSP + cp;
                const float* src = imgP + (by0 - 2 + r) * Ww + (bx0 - 2 + cp);
#pragma unroll
                for (int f = 0; f < Ff; ++f) {
                    float2 t = *(const float2*)&src[f * Nn];
                    va[k][0][f] = t.x; va[k][1][f] = t.y;
                }
            }
        }
#pragma unroll
        for (int k = 0; k < 3; ++k) {
            if (act[k]) {
                PROCPT(va[k][0], sis[k], true);
                PROCPT(va[k][1], sis[k] + 1, true);
            }
        }
    } else {
        // Border tiles (23%): guarded sequential path.
#pragma unroll
        for (int k = 0; k < 3; ++k) {
            const int i2 = tid + k * NT;
            if (i2 < 648) {
                const int r  = (unsigned)i2 / 18;
                const int cp = ((unsigned)i2 % 18) * 2;
                const int gy = by0 - 2 + r, gx = bx0 - 2 + cp;
                const int si = r * RSP + cp;
                float v0[Ff], v1[Ff];
                const bool okY = (unsigned)gy < Hh;
                const bool ok0 = okY & ((unsigned)gx < Ww);
                const bool ok1 = okY & ((unsigned)(gx + 1) < Ww);
                const float* src = imgP + gy * Ww + gx;
                if (ok0) {
#pragma unroll
                    for (int f = 0; f < Ff; ++f) v0[f] = src[f * Nn];
                }
                if (ok1) {
#pragma unroll
                    for (int f = 0; f < Ff; ++f) v1[f] = src[f * Nn + 1];
                }
                PROCPT(v0, si, ok0);
                PROCPT(v1, si + 1, ok1);
            }
        }
    }
    __syncthreads();

    // ---- Phase 2a: all 16 window b128 reads issued upfront, then 30 dots ----
    const int r2 = tid >> 4, c2 = tid & 15;
    const int gy0 = by0 + 2 * r2, gx0 = bx0 + 2 * c2;
    const int wb  = (2 * r2 + 1) * RSP + (2 * c2 + 1);   // fm idx of window (0,0)

    FmPt w0[4], w1[4], w2[4], w3[4];
#pragma unroll
    for (int ci = 0; ci < 4; ++ci) w0[ci] = LD(wb + ci);
#pragma unroll
    for (int ci = 0; ci < 4; ++ci) w1[ci] = LD(wb + RSP + ci);
#pragma unroll
    for (int ci = 0; ci < 4; ++ci) w2[ci] = LD(wb + 2 * RSP + ci);
#pragma unroll
    for (int ci = 0; ci < 4; ++ci) w3[ci] = LD(wb + 3 * RSP + ci);

    float e0[9], e1[9], e2[9], e3[9];
    // px0 = w1[1]
    e0[0] = ew_of(dotfm(w1[1], w0[0])); e0[1] = ew_of(dotfm(w1[1], w0[1])); e0[2] = ew_of(dotfm(w1[1], w0[2]));
    e0[3] = ew_of(dotfm(w1[1], w1[0])); e0[4] = ew_of(dotfm(w1[1], w1[1])); e0[5] = ew_of(dotfm(w1[1], w1[2]));
    e0[6] = ew_of(dotfm(w1[1], w2[0])); e0[7] = ew_of(dotfm(w1[1], w2[1])); e0[8] = ew_of(dotfm(w1[1], w2[2]));
    // px1 = w1[2]  (shares W-edge with px0)
    e1[0] = ew_of(dotfm(w1[2], w0[1])); e1[1] = ew_of(dotfm(w1[2], w0[2])); e1[2] = ew_of(dotfm(w1[2], w0[3]));
    e1[3] = e0[5];                      e1[4] = ew_of(dotfm(w1[2], w1[2])); e1[5] = ew_of(dotfm(w1[2], w1[3]));
    e1[6] = ew_of(dotfm(w1[2], w2[1])); e1[7] = ew_of(dotfm(w1[2], w2[2])); e1[8] = ew_of(dotfm(w1[2], w2[3]));
    // px2 = w2[1]  (shares N=e0.S, NE=e1.SW)
    e2[0] = ew_of(dotfm(w2[1], w1[0])); e2[1] = e0[7];                      e2[2] = e1[6];
    e2[3] = ew_of(dotfm(w2[1], w2[0])); e2[4] = ew_of(dotfm(w2[1], w2[1])); e2[5] = ew_of(dotfm(w2[1], w2[2]));
    e2[6] = ew_of(dotfm(w2[1], w3[0])); e2[7] = ew_of(dotfm(w2[1], w3[1])); e2[8] = ew_of(dotfm(w2[1], w3[2]));
    // px3 = w2[2]  (shares NW=e0.SE, N=e1.S, W=e2.E)
    e3[0] = e0[8];                      e3[1] = e1[7];                      e3[2] = ew_of(dotfm(w2[2], w1[3]));
    e3[3] = e2[5];                      e3[4] = ew_of(dotfm(w2[2], w2[2])); e3[5] = ew_of(dotfm(w2[2], w2[3]));
    e3[6] = ew_of(dotfm(w2[2], w3[1])); e3[7] = ew_of(dotfm(w2[2], w3[2])); e3[8] = ew_of(dotfm(w2[2], w3[3]));

    if (border) {   // mask edges leaving the image
#pragma unroll
        for (int j = 0; j < 9; ++j) {
            int dy = j / 3 - 1, dx = j % 3 - 1;
            if (!(((unsigned)(gy0 + dy)     < Hh) & ((unsigned)(gx0 + dx)     < Ww))) e0[j] = 0.f;
            if (!(((unsigned)(gy0 + dy)     < Hh) & ((unsigned)(gx0 + 1 + dx) < Ww))) e1[j] = 0.f;
            if (!(((unsigned)(gy0 + 1 + dy) < Hh) & ((unsigned)(gx0 + dx)     < Ww))) e2[j] = 0.f;
            if (!(((unsigned)(gy0 + 1 + dy) < Hh) & ((unsigned)(gx0 + 1 + dx) < Ww))) e3[j] = 0.f;
        }
    }

    float deg0 = 0.f, deg1 = 0.f, deg2 = 0.f, deg3 = 0.f;
#pragma unroll
    for (int j = 0; j < 9; ++j) { deg0 += e0[j]; deg1 += e1[j]; deg2 += e2[j]; deg3 += e3[j]; }
    const float dp0 = 1.0f / sqrtf(deg0);
    const float dp1 = 1.0f / sqrtf(deg1);
    const float dp2 = 1.0f / sqrtf(deg2);
    const float dp3 = 1.0f / sqrtf(deg3);
    {
        const int db = (2 * r2 + 1) * DSP + (2 * c2 + 1);
        dv[db]           = __float2half_rn(dp0);
        dv[db + 1]       = __float2half_rn(dp1);
        dv[db + DSP]     = __float2half_rn(dp2);
        dv[db + DSP + 1] = __float2half_rn(dp3);
    }

    // ---- Phase 2b: halo ring (132 px): deg only; OOB slots -> 1.0 ----
    if (tid < 132) {
        int r, c;
        if (tid < 34)       { r = 0;        c = tid;       }
        else if (tid < 68)  { r = 33;       c = tid - 34;  }
        else if (tid < 100) { r = tid - 67; c = 0;         }
        else                { r = tid - 99; c = 33;        }
        int gy = by0 - 1 + r, gx = bx0 - 1 + c;
        float d = 1.0f;
        if ((unsigned)gy < Hh && (unsigned)gx < Ww) {
            int fi = (r + 1) * RSP + (c + 1);
            FmPt a = LD(fi);
            float deg = 0.f;
#pragma unroll
            for (int j = 0; j < 9; ++j) {
                int dy = j / 3 - 1, dx = j % 3 - 1;
                FmPt q = LD(fi + dy * RSP + dx);
                float e = ew_of(dotfm(a, q));
                bool valid = ((unsigned)(gy + dy) < Hh) & ((unsigned)(gx + dx) < Ww);
                deg += valid ? e : 0.f;
            }
            d = 1.0f / sqrtf(deg);
        }
        dv[r * DSP + c] = __float2half_rn(d);
    }
    __syncthreads();

    // ---- Phase 3: sig windows (L2-hot); dv via aligned half2 pairs ----
    int ry[4];
#pragma unroll
    for (int i = 0; i < 4; ++i) ry[i] = min(max(gy0 - 1 + i, 0), Hh - 1) * Ww;
    const int cxm = max(gx0 - 1, 0), cxp = min(gx0 + 2, Ww - 1);

    float s0[16], s1[16];
#pragma unroll
    for (int i = 0; i < 4; ++i) {
        float2 mid = *(const float2*)&sgp[ry[i] + gx0];
        s0[4 * i]     = sgp[ry[i] + cxm];
        s0[4 * i + 1] = mid.x;
        s0[4 * i + 2] = mid.y;
        s0[4 * i + 3] = sgp[ry[i] + cxp];
    }
#pragma unroll
    for (int i = 0; i < 4; ++i) {
        float2 mid = *(const float2*)&sgp[Nn + ry[i] + gx0];
        s1[4 * i]     = sgp[Nn + ry[i] + cxm];
        s1[4 * i + 1] = mid.x;
        s1[4 * i + 2] = mid.y;
        s1[4 * i + 3] = sgp[Nn + ry[i] + cxp];
    }

    float dvf[16];
    {
        const int db = 2 * r2 * DSP + 2 * c2;    // even -> aligned half2 pairs
#pragma unroll
        for (int i = 0; i < 4; ++i) {
            __half2 pa = *(const __half2*)&dv[db + i * DSP];
            __half2 pb = *(const __half2*)&dv[db + i * DSP + 2];
            dvf[4 * i]     = __low2float(pa);
            dvf[4 * i + 1] = __high2float(pa);
            dvf[4 * i + 2] = __low2float(pb);
            dvf[4 * i + 3] = __high2float(pb);
        }
    }
#pragma unroll
    for (int j = 0; j < 9; ++j) {
        const int k0 = (j / 3) * 4 + (j % 3);
        e0[j] = dp0 * e0[j] * dvf[k0];
        e1[j] = dp1 * e1[j] * dvf[k0 + 1];
        e2[j] = dp2 * e2[j] * dvf[k0 + 4];
        e3[j] = dp3 * e3[j] * dvf[k0 + 5];
    }

    // c2 loads issued here -> hidden under the c0/c1 aggregation below
    float s2[16];
#pragma unroll
    for (int i = 0; i < 4; ++i) {
        float2 mid = *(const float2*)&sgp[2 * Nn + ry[i] + gx0];
        s2[4 * i]     = sgp[2 * Nn + ry[i] + cxm];
        s2[4 * i + 1] = mid.x;
        s2[4 * i + 2] = mid.y;
        s2[4 * i + 3] = sgp[2 * Nn + ry[i] + cxp];
    }

    float* o = out + (size_t)bg * Cc * Nn;
    const int p = gy0 * Ww + gx0;
    {
        float a0 = 0.f, a1 = 0.f, a2 = 0.f, a3 = 0.f;
        float b0 = 0.f, b1 = 0.f, b2 = 0.f, b3 = 0.f;
#pragma unroll
        for (int j = 0; j < 9; ++j) {
            const int k0 = (j / 3) * 4 + (j % 3);
            a0 = fmaf(e0[j], s0[k0],     a0);
            a1 = fmaf(e1[j], s0[k0 + 1], a1);
            a2 = fmaf(e2[j], s0[k0 + 4], a2);
            a3 = fmaf(e3[j], s0[k0 + 5], a3);
            b0 = fmaf(e0[j], s1[k0],     b0);
            b1 = fmaf(e1[j], s1[k0 + 1], b1);
            b2 = fmaf(e2[j], s1[k0 + 4], b2);
            b3 = fmaf(e3[j], s1[k0 + 5], b3);
        }
        *(float2*)&o[p]           = make_float2(s0[5] - a0, s0[6]  - a1);
        *(float2*)&o[p + Ww]      = make_float2(s0[9] - a2, s0[10] - a3);
        *(float2*)&o[Nn + p]      = make_float2(s1[5] - b0, s1[6]  - b1);
        *(float2*)&o[Nn + p + Ww] = make_float2(s1[9] - b2, s1[10] - b3);
    }
    {
        float c0 = 0.f, c1 = 0.f, c2v = 0.f, c3 = 0.f;
#pragma unroll
        for (int j = 0; j < 9; ++j) {
            const int k0 = (j / 3) * 4 + (j % 3);
            c0  = fmaf(e0[j], s2[k0],     c0);
            c1  = fmaf(e1[j], s2[k0 + 1], c1);
            c2v = fmaf(e2[j], s2[k0 + 4], c2v);
            c3  = fmaf(e3[j], s2[k0 + 5], c3);
        }
        *(float2*)&o[2 * Nn + p]      = make_float2(s2[5] - c0,  s2[6]  - c1);
        *(float2*)&o[2 * Nn + p + Ww] = make_float2(s2[9] - c2v, s2[10] - c3);
    }
}

extern "C" void kernel_launch(void* const* d_in, const int* in_sizes, int n_in,
                              void* d_out, int out_size, void* d_ws, size_t ws_size,
                              hipStream_t stream) {
    const float* img = (const float*)d_in[0];   // (B,G,F,H,W)
    const float* sig = (const float*)d_in[1];   // (B,G,C,H,W)
    const float* M   = (const float*)d_in[2];   // (G,F,F)
    float* out = (float*)d_out;

    fused_kernel<<<dim3(256 * Bb * Gg), NT, 0, stream>>>(img, M, sig, out);
}